// Round 4
// baseline (252.115 us; speedup 1.0000x reference)
//
#include <hip/hip_runtime.h>

#define NB 16
#define NC 256
#define NH 64
#define NW 64
#define PATCH 9
#define TROWS 4
#define CHST (NH * NW)          // channel plane stride (floats)
#define SPLIT 2
#define CBLK (NC / SPLIT)       // 128 channels per wave-group
#define DEPTH 4                 // register prefetch pipeline depth
#define BT 384                  // 6 waves: w%3 -> di triple member, w/3 -> channel half

// DPP 16-lane-row shifts (CDNA):
//   row_shr:1 (0x111): lane l <- lane l-1 (first lane of 16-row -> 0)
//   row_shl:1 (0x101): lane l <- lane l+1 (last  lane of 16-row -> 0)
// 16-lane col-groups == DPP rows, so shifted-in zeros give horizontal
// zero-padding of y for free. (Direction verified in R3: passed.)
__device__ __forceinline__ float from_prev_lane(float v) {
    return __int_as_float(__builtin_amdgcn_update_dpp(
        0, __float_as_int(v), 0x111, 0xF, 0xF, true));
}
__device__ __forceinline__ float from_next_lane(float v) {
    return __int_as_float(__builtin_amdgcn_update_dpp(
        0, __float_as_int(v), 0x101, 0xF, 0xF, true));
}

// out[b, di*9+dj, i, j] = (1/C) * sum_c x[b,c,i,j] * y[b,c,i+di-4, j+dj-4]
__global__ void __launch_bounds__(BT, 4)
corr_kernel(const float* __restrict__ x, const float* __restrict__ y,
            float* __restrict__ out)
{
    // reduction buffer: [dj][192 threads][4 floats] -> lane-consecutive 16B,
    // canonical conflict-free ds_*_b128 pattern. 27648 B.
    __shared__ __align__(16) float red[PATCH * 192 * 4];

    const int tid  = threadIdx.x;
    const int wv   = tid >> 6;          // 0..5
    const int ln   = tid & 63;
    const int q    = wv / 3;            // channel half (0: c<128, 1: c>=128)
    const int w3   = wv % 3;            // member of di triple
    const int prow = ln >> 4;           // pixel row within tile
    const int j0   = (ln & 15) << 2;    // col base

    const int blk = blockIdx.x;         // 768 blocks
    const int g   = blk >> 8;           // di triple 0..2
    const int rem = blk & 255;
    const int b   = rem >> 4;
    const int t   = rem & 15;
    const int r0  = t * TROWS;

    const int di  = g * 3 + w3;         // 0..8, wave-uniform
    const int i   = r0 + prow;          // output pixel row
    const int yr0 = i + di - 4;         // y row this thread needs
    const bool rv = (yr0 >= 0) && (yr0 < NH);
    const int yr  = rv ? yr0 : i;       // clamp: garbage OK, masked at the end

    const size_t cbase = (size_t)(b * NC + q * CBLK);
    const float* xp = x + (cbase * NH + i ) * NW + j0;
    const float* yp = y + (cbase * NH + yr) * NW + j0;

    float acc[PATCH][4];
    #pragma unroll
    for (int dj = 0; dj < PATCH; ++dj)
        #pragma unroll
        for (int tt = 0; tt < 4; ++tt) acc[dj][tt] = 0.0f;

    // depth-4 register pipeline: 8 loads in flight, no LDS, no barriers
    float4 X[DEPTH], Y[DEPTH];
    #pragma unroll
    for (int d = 0; d < DEPTH; ++d) {
        X[d] = *(const float4*)(xp + (size_t)d * CHST);
        Y[d] = *(const float4*)(yp + (size_t)d * CHST);
    }

    #pragma unroll 4
    for (int c = 0; c < CBLK; ++c) {
        const int k = c & (DEPTH - 1);
        const float4 xa = X[k];
        const float4 ya = Y[k];

        // refill slot k (scalar-uniform offset; tail reloads current channel)
        const int cn = (c + DEPTH < CBLK) ? (c + DEPTH) : c;
        X[k] = *(const float4*)(xp + (size_t)cn * CHST);
        Y[k] = *(const float4*)(yp + (size_t)cn * CHST);

        // 12-float window [j0-4, j0+8): neighbors via DPP, edges auto-zero
        float wnd[12];
        wnd[0]  = from_prev_lane(ya.x);  wnd[1]  = from_prev_lane(ya.y);
        wnd[2]  = from_prev_lane(ya.z);  wnd[3]  = from_prev_lane(ya.w);
        wnd[4]  = ya.x;                  wnd[5]  = ya.y;
        wnd[6]  = ya.z;                  wnd[7]  = ya.w;
        wnd[8]  = from_next_lane(ya.x);  wnd[9]  = from_next_lane(ya.y);
        wnd[10] = from_next_lane(ya.z);  wnd[11] = from_next_lane(ya.w);

        const float xs[4] = {xa.x, xa.y, xa.z, xa.w};
        #pragma unroll
        for (int dj = 0; dj < PATCH; ++dj)
            #pragma unroll
            for (int tt = 0; tt < 4; ++tt)
                acc[dj][tt] = fmaf(xs[tt], wnd[tt + dj], acc[dj][tt]);
    }

    // cross-half reduction through LDS (single barrier in the whole kernel)
    if (q == 1) {
        const int l = tid - 192;
        #pragma unroll
        for (int dj = 0; dj < PATCH; ++dj)
            *(float4*)&red[(dj * 192 + l) * 4] =
                make_float4(acc[dj][0], acc[dj][1], acc[dj][2], acc[dj][3]);
    }
    __syncthreads();
    if (q == 0) {
        // rv is identical for the partner thread (same di,i) -> mask after sum
        const float sc = rv ? (1.0f / (float)NC) : 0.0f;
        float* op = out + (((size_t)b * (PATCH * PATCH) + di * PATCH) * NH + i) * NW + j0;
        #pragma unroll
        for (int dj = 0; dj < PATCH; ++dj) {
            const float4 r = *(const float4*)&red[(dj * 192 + tid) * 4];
            float4 o = make_float4((acc[dj][0] + r.x) * sc,
                                   (acc[dj][1] + r.y) * sc,
                                   (acc[dj][2] + r.z) * sc,
                                   (acc[dj][3] + r.w) * sc);
            *(float4*)(op + (size_t)dj * CHST) = o;
        }
    }
}

extern "C" void kernel_launch(void* const* d_in, const int* in_sizes, int n_in,
                              void* d_out, int out_size, void* d_ws, size_t ws_size,
                              hipStream_t stream)
{
    const float* x = (const float*)d_in[0];
    const float* y = (const float*)d_in[1];
    float* out = (float*)d_out;

    dim3 grid(3 * NB * (NH / TROWS));   // 3 di-triples * 16 b * 16 row-tiles = 768
    dim3 block(BT);                     // 6 waves
    hipLaunchKernelGGL(corr_kernel, grid, block, 0, stream, x, y, out);
}

// Round 5
// 217.426 us; speedup vs baseline: 1.1595x; 1.1595x over previous
//
#include <hip/hip_runtime.h>

#define NB 16
#define NC 256
#define NH 64
#define NW 64
#define PATCH 9
#define TROWS 4
#define CHST (NH * NW)          // channel plane stride (floats)
#define DEPTH 8                 // register prefetch pipeline depth (16 loads in flight)
#define BT 192                  // 3 waves; wave w handles di = 3*g + w

// DPP 16-lane-row shifts (CDNA), direction verified on HW in R3:
//   row_shr:1 (0x111): lane l <- lane l-1 (first lane of 16-row -> 0)
//   row_shl:1 (0x101): lane l <- lane l+1 (last  lane of 16-row -> 0)
// 16-lane col-groups == DPP rows, so shifted-in zeros give horizontal
// zero-padding of y for free.
__device__ __forceinline__ float from_prev_lane(float v) {
    return __int_as_float(__builtin_amdgcn_update_dpp(
        0, __float_as_int(v), 0x111, 0xF, 0xF, true));
}
__device__ __forceinline__ float from_next_lane(float v) {
    return __int_as_float(__builtin_amdgcn_update_dpp(
        0, __float_as_int(v), 0x101, 0xF, 0xF, true));
}

// out[b, di*9+dj, i, j] = (1/C) * sum_c x[b,c,i,j] * y[b,c,i+di-4, j+dj-4]
__global__ void __launch_bounds__(BT, 2)   // allow up to 256 VGPR: pipeline must stay in regs
corr_kernel(const float* __restrict__ x, const float* __restrict__ y,
            float* __restrict__ out)
{
    const int tid  = threadIdx.x;
    const int w    = tid >> 6;           // wave 0..2
    const int ln   = tid & 63;
    const int prow = ln >> 4;            // pixel row within tile (DPP-row index)
    const int j0   = (ln & 15) << 2;     // col base, lane order == col order

    // blk = g*256 + b*16 + t  (same traffic pattern as R3: FETCH ~133 MB)
    const int blk = blockIdx.x;
    const int g   = blk >> 8;            // di triple 0..2
    const int rem = blk & 255;
    const int b   = rem >> 4;
    const int t   = rem & 15;
    const int r0  = t * TROWS;

    const int di  = g * 3 + w;           // 0..8, wave-uniform
    const int i   = r0 + prow;           // output pixel row
    const int yr0 = i + di - 4;          // y row this thread needs
    const bool rv = (yr0 >= 0) && (yr0 < NH);
    const int yr  = rv ? yr0 : i;        // clamp: garbage summed, masked at the end

    const float* xp = x + ((size_t)(b * NC) * NH + i ) * NW + j0;
    const float* yp = y + ((size_t)(b * NC) * NH + yr) * NW + j0;

    float acc[PATCH][4];
    #pragma unroll
    for (int dj = 0; dj < PATCH; ++dj)
        #pragma unroll
        for (int tt = 0; tt < 4; ++tt) acc[dj][tt] = 0.0f;

    // prime the depth-8 rolling pipeline: 16 loads in flight
    float4 X[DEPTH], Y[DEPTH];
    #pragma unroll
    for (int d = 0; d < DEPTH; ++d) {
        X[d] = *(const float4*)(xp + (size_t)d * CHST);
        Y[d] = *(const float4*)(yp + (size_t)d * CHST);
    }

    // unroll by the full pipeline period so slot indices are compile-time
    #pragma unroll 8
    for (int c = 0; c < NC; ++c) {
        const int k = c & (DEPTH - 1);
        const float4 xa = X[k];          // waitcnt lands here: load issued 8 iters ago
        const float4 ya = Y[k];

        // refill slot k early (uniform channel offset -> scalar-folded addressing;
        // tail iterations harmlessly reload the current channel)
        const int cn = (c + DEPTH < NC) ? (c + DEPTH) : c;
        X[k] = *(const float4*)(xp + (size_t)cn * CHST);
        Y[k] = *(const float4*)(yp + (size_t)cn * CHST);

        // 12-float window [j0-4, j0+8): neighbors via DPP, edges auto-zero
        float wnd[12];
        wnd[0]  = from_prev_lane(ya.x);  wnd[1]  = from_prev_lane(ya.y);
        wnd[2]  = from_prev_lane(ya.z);  wnd[3]  = from_prev_lane(ya.w);
        wnd[4]  = ya.x;                  wnd[5]  = ya.y;
        wnd[6]  = ya.z;                  wnd[7]  = ya.w;
        wnd[8]  = from_next_lane(ya.x);  wnd[9]  = from_next_lane(ya.y);
        wnd[10] = from_next_lane(ya.z);  wnd[11] = from_next_lane(ya.w);

        const float xs[4] = {xa.x, xa.y, xa.z, xa.w};
        #pragma unroll
        for (int dj = 0; dj < PATCH; ++dj)
            #pragma unroll
            for (int tt = 0; tt < 4; ++tt)
                acc[dj][tt] = fmaf(xs[tt], wnd[tt + dj], acc[dj][tt]);
    }

    // epilogue: mask invalid y-rows (their acc is garbage), scale, float4 stores
    const float sc = rv ? (1.0f / (float)NC) : 0.0f;
    float* op = out + (((size_t)b * (PATCH * PATCH) + di * PATCH) * NH + i) * NW + j0;
    #pragma unroll
    for (int dj = 0; dj < PATCH; ++dj) {
        float4 o = make_float4(acc[dj][0] * sc, acc[dj][1] * sc,
                               acc[dj][2] * sc, acc[dj][3] * sc);
        *(float4*)(op + (size_t)dj * CHST) = o;
    }
}

extern "C" void kernel_launch(void* const* d_in, const int* in_sizes, int n_in,
                              void* d_out, int out_size, void* d_ws, size_t ws_size,
                              hipStream_t stream)
{
    const float* x = (const float*)d_in[0];
    const float* y = (const float*)d_in[1];
    float* out = (float*)d_out;

    dim3 grid(3 * NB * (NH / TROWS));   // 3 di-triples * 16 b * 16 row-tiles = 768
    dim3 block(BT);                     // 3 waves, no LDS, no barriers
    hipLaunchKernelGGL(corr_kernel, grid, block, 0, stream, x, y, out);
}